// Round 9
// baseline (592.485 us; speedup 1.0000x reference)
//
#include <hip/hip_runtime.h>

#define CCH 16
#define DD 64
#define HH 96
#define WW 96
#define HW (HH*WW)
#define DHW (DD*HH*WW)   // 589824
#define CH4 (DHW/4)      // 147456
#define NTH 384
#define DCH 8            // depth outputs per block
#define NBY (DD/DCH)     // 8 depth chunks
#define KTR 1.08f        // 27 * k_harris (S unscaled by 1/27; ranking-invariant)

// DPP row16 shifts: thread layout is lh-fast (lh = tid & 15), so a DPP row of
// 16 lanes == one h-column; bound_ctrl=true zero-fills at row ends (filled
// sites only feed non-emitted outputs). Harris is invariant to an up/down swap
// (every term has even degree in each gradient; a swap only flips gy's sign).
__device__ __forceinline__ float dpp_up(float v) {
    return __int_as_float(__builtin_amdgcn_update_dpp(
        0, __float_as_int(v), 0x111 /*row_shr:1*/, 0xF, 0xF, true));
}
__device__ __forceinline__ float dpp_dn(float v) {
    return __int_as_float(__builtin_amdgcn_update_dpp(
        0, __float_as_int(v), 0x101 /*row_shl:1*/, 0xF, 0xF, true));
}

__device__ __forceinline__ void load4(float v[4], const float* __restrict__ xc,
                                      int e, int woff, bool rowok) {
    if (rowok && (unsigned)e < DD) {
        const float4 t = *(const float4*)(xc + (size_t)e * HW + woff);
        v[0] = t.x; v[1] = t.y; v[2] = t.z; v[3] = t.w;
    } else {
        v[0] = v[1] = v[2] = v[3] = 0.f;
    }
}

// Depth-sweep separable Harris; thread owns 4 consecutive w sites (float4);
// w-convs register-internal + LDS edge exchange; h-convs via DPP (VALU pipe).
// Block: 384 thr = 16 lh x 24 lc (full W=96, h-tile 12+2 halo).
// launch_bounds(384,8): cap VGPR at 64 -> 32 wave slots/CU; grid 1024 blocks
// -> 4-5 blocks/CU = 24-30 waves/CU (vs 12 at VGPR=72), double latency hiding.
__global__ __launch_bounds__(NTH, 8)
void harris_sum_kernel(const float* __restrict__ x, float* __restrict__ pp) {
    __shared__ float eA[4][NTH];    // A.x, A.w, Dz.x, Dz.w edges
    __shared__ float eP[12][NTH];   // P[f].x, P[f].w edges
    __shared__ float red[6];

    const int tid = threadIdx.x;
    const int lh = tid & 15, lc = tid >> 4;
    const int c  = blockIdx.z;
    const int H0 = blockIdx.x * 12;
    const int o0 = blockIdx.y * DCH;
    const int gh = H0 + lh - 2;
    const bool rowok = ((unsigned)gh < HH);
    const float mask = rowok ? 1.f : 0.f;   // zero products at OOB rows (box zero-pad)
    const float* xc = x + (size_t)c * DHW;
    const int woff = gh * WW + (lc << 2);

    // rolling x window: xp=x(e-1), xm=x(e), xn=x(e+1); xn loaded in-loop
    float xp[4], xm[4], xn[4];
    load4(xp, xc, o0 - 2, woff, rowok);
    load4(xm, xc, o0 - 1, woff, rowok);

    float s2m1[6][4], s2m2[6][4];
    #pragma unroll
    for (int f = 0; f < 6; ++f)
        #pragma unroll
        for (int i = 0; i < 4; ++i) { s2m1[f][i] = 0.f; s2m2[f][i] = 0.f; }
    float hs = 0.f;
    const bool emit_row = (lh >= 2) && (lh <= 13);

    for (int e = o0 - 1; e <= o0 + DCH; ++e) {   // 10 slices -> 8 output slices
        load4(xn, xc, e + 1, woff, rowok);       // x(e+1); waves hide the latency

        float s2c[6][4];
        if ((unsigned)e < DD) {                  // block-uniform branch
            float A[4], Dz[4];
            #pragma unroll
            for (int i = 0; i < 4; ++i) {
                A[i]  = xp[i] + xm[i] + xn[i];   // depth [1,1,1]
                Dz[i] = xn[i] - xp[i];           // depth [-1,0,1]
            }
            eA[0][tid] = A[0];  eA[1][tid] = A[3];
            eA[2][tid] = Dz[0]; eA[3][tid] = Dz[3];
            __syncthreads();
            float Alw = (lc > 0)  ? eA[1][tid - 16] : 0.f;
            float Dlw = (lc > 0)  ? eA[3][tid - 16] : 0.f;
            float Arx = (lc < 23) ? eA[0][tid + 16] : 0.f;
            float Drx = (lc < 23) ? eA[2][tid + 16] : 0.f;
            const float Al[4] = {Alw, A[0], A[1], A[2]};
            const float Ar[4] = {A[1], A[2], A[3], Arx};
            const float Dl[4] = {Dlw, Dz[0], Dz[1], Dz[2]};
            const float Dr[4] = {Dz[1], Dz[2], Dz[3], Drx};

            float P[6][4];
            #pragma unroll
            for (int i = 0; i < 4; ++i) {
                float Sx = Ar[i] - Al[i];               // w [-1,0,1] on A
                float Tx = Al[i] + 2.f*A[i] + Ar[i];    // w [1,2,1]  on A
                float Td = Dl[i] + Dz[i] + Dr[i];       // w [1,1,1]  on Dz
                float gx = (dpp_up(Sx) + 2.f*Sx + dpp_dn(Sx)) * mask;  // h [1,2,1]
                float gy = (dpp_dn(Tx) - dpp_up(Tx)) * mask;           // h [-1,0,1]
                float gz = (dpp_up(Td) + Td + dpp_dn(Td)) * mask;      // h [1,1,1]
                P[0][i] = gx*gx; P[1][i] = gy*gy; P[2][i] = gz*gz;
                P[3][i] = gx*gy; P[4][i] = gx*gz; P[5][i] = gy*gz;
            }
            #pragma unroll
            for (int f = 0; f < 6; ++f) { eP[2*f][tid] = P[f][0]; eP[2*f+1][tid] = P[f][3]; }
            __syncthreads();
            #pragma unroll
            for (int f = 0; f < 6; ++f) {
                float pl = (lc > 0)  ? eP[2*f+1][tid - 16] : 0.f;
                float pr = (lc < 23) ? eP[2*f][tid + 16]   : 0.f;
                float R0 = pl      + P[f][0] + P[f][1];
                float R1 = P[f][0] + P[f][1] + P[f][2];
                float R2 = P[f][1] + P[f][2] + P[f][3];
                float R3 = P[f][2] + P[f][3] + pr;
                s2c[f][0] = dpp_up(R0) + R0 + dpp_dn(R0);   // h [1,1,1]
                s2c[f][1] = dpp_up(R1) + R1 + dpp_dn(R1);
                s2c[f][2] = dpp_up(R2) + R2 + dpp_dn(R2);
                s2c[f][3] = dpp_up(R3) + R3 + dpp_dn(R3);
            }
        } else {
            #pragma unroll
            for (int f = 0; f < 6; ++f)
                #pragma unroll
                for (int i = 0; i < 4; ++i) s2c[f][i] = 0.f;
        }

        if (e > o0 && emit_row) {   // emit output slice o = e-1
            #pragma unroll
            for (int i = 0; i < 4; ++i) {
                float sxx = s2m2[0][i] + s2m1[0][i] + s2c[0][i];
                float syy = s2m2[1][i] + s2m1[1][i] + s2c[1][i];
                float szz = s2m2[2][i] + s2m1[2][i] + s2c[2][i];
                float sxy = s2m2[3][i] + s2m1[3][i] + s2c[3][i];
                float sxz = s2m2[4][i] + s2m1[4][i] + s2c[4][i];
                float syz = s2m2[5][i] + s2m1[5][i] + s2c[5][i];
                float det = sxx*(syy*szz - syz*syz)
                          - sxy*(sxy*szz - syz*sxz)
                          + sxz*(sxy*syz - syy*sxz);
                float tr = sxx + syy + szz;
                hs += det - KTR * tr * tr;   // unscaled by 27^-3: ranking-invariant
            }
        }
        #pragma unroll
        for (int f = 0; f < 6; ++f)
            #pragma unroll
            for (int i = 0; i < 4; ++i) { s2m2[f][i] = s2m1[f][i]; s2m1[f][i] = s2c[f][i]; }
        #pragma unroll
        for (int i = 0; i < 4; ++i) { xp[i] = xm[i]; xm[i] = xn[i]; }
    }

    // block reduce -> per-block partial slot (no atomics, no ws init needed)
    #pragma unroll
    for (int o = 32; o > 0; o >>= 1) hs += __shfl_down(hs, o, 64);
    if ((tid & 63) == 0) red[tid >> 6] = hs;
    __syncthreads();
    if (tid == 0)
        pp[c * (NBY * 8) + blockIdx.y * 8 + blockIdx.x] =
            red[0] + red[1] + red[2] + red[3] + red[4] + red[5];
}

// Sum 64 partials/channel, top-8 select (strict >: stable ties), gather copy.
__global__ __launch_bounds__(256)
void gather_topk_kernel(const float* __restrict__ x, const float* __restrict__ pp,
                        float4* __restrict__ out) {
    __shared__ float pv[CCH];
    __shared__ int sidx[8];
    const int tid = threadIdx.x;
    if (tid < CCH) {
        float s = 0.f;
        #pragma unroll
        for (int j = 0; j < NBY * 8; ++j) s += pp[tid * (NBY * 8) + j];
        pv[tid] = s;   // fixed order -> deterministic across blocks
    }
    __syncthreads();
    if (tid == 0) {
        bool used[CCH];
        #pragma unroll
        for (int i = 0; i < CCH; ++i) used[i] = false;
        for (int j = 0; j < 8; ++j) {
            int best = 0; float bv = -__builtin_inff();
            for (int i = 0; i < CCH; ++i)
                if (!used[i] && pv[i] > bv) { bv = pv[i]; best = i; }
            used[best] = true;
            sidx[j] = best;
        }
    }
    __syncthreads();
    const int j   = blockIdx.y;                      // 0..7
    const int pos = blockIdx.x * 256 + tid;          // 576*256 == CH4 exact
    const int cidx = sidx[j];
    const float4* src = (const float4*)(x + (size_t)cidx * DHW);
    out[(size_t)j * CH4 + pos] = src[pos];
}

extern "C" void kernel_launch(void* const* d_in, const int* in_sizes, int n_in,
                              void* d_out, int out_size, void* d_ws, size_t ws_size,
                              hipStream_t stream) {
    const float* x = (const float*)d_in[0];
    float4* out = reinterpret_cast<float4*>(d_out);
    float* pp = (float*)d_ws;                        // 1024 per-block partials (4 KB)

    dim3 g1(8, NBY, CCH);                            // 1024 blocks
    harris_sum_kernel<<<g1, NTH, 0, stream>>>(x, pp);

    dim3 g2(CH4 / 256, 8, 1);                        // (576, 8)
    gather_topk_kernel<<<g2, 256, 0, stream>>>(x, pp, out);
}

// Round 10
// 161.700 us; speedup vs baseline: 3.6641x; 3.6641x over previous
//
#include <hip/hip_runtime.h>

#define CCH 16
#define DD 64
#define HH 96
#define WW 96
#define HW (HH*WW)
#define DHW (DD*HH*WW)   // 589824
#define CH4 (DHW/4)      // 147456
#define NTH 768          // 16 lh x 48 lc, 2 w-sites per thread
#define DCH 16           // depth outputs per block
#define NBY (DD/DCH)     // 4 depth chunks
#define KTR 1.08f        // 27 * k_harris (S unscaled by 1/27; ranking-invariant)
#define INV27C (1.f/19683.f)

// DPP row16 shifts: thread layout is lh-fast (lh = tid & 15), so a DPP row of
// 16 lanes == one h-column; bound_ctrl=true zero-fills at row ends (filled
// sites only feed non-emitted outputs). Harris is invariant to an up/down swap
// (every term has even degree in each gradient; a swap only flips gy's sign).
__device__ __forceinline__ float dpp_up(float v) {
    return __int_as_float(__builtin_amdgcn_update_dpp(
        0, __float_as_int(v), 0x111 /*row_shr:1*/, 0xF, 0xF, true));
}
__device__ __forceinline__ float dpp_dn(float v) {
    return __int_as_float(__builtin_amdgcn_update_dpp(
        0, __float_as_int(v), 0x101 /*row_shl:1*/, 0xF, 0xF, true));
}

__device__ __forceinline__ void load2(float v[2], const float* __restrict__ xc,
                                      int e, int woff, bool rowok) {
    if (rowok && (unsigned)e < DD) {
        const float2 t = *(const float2*)(xc + (size_t)e * HW + woff);
        v[0] = t.x; v[1] = t.y;
    } else {
        v[0] = v[1] = 0.f;
    }
}

// Depth-sweep separable Harris; thread owns 2 consecutive w sites (float2).
// 2 sites/thread halves the S2 depth-history to 24 VGPRs -> natural alloc
// should land <=64 VGPR -> 8 waves/SIMD -> 2 blocks x 12 waves = 24 waves/CU
// (vs 12 at the 4-site/72-VGPR variant). w-convs register-internal + LDS edge
// exchange at tid+-16; h-convs via DPP row shifts (VALU pipe).
// Block: 768 thr = 16 lh x 48 lc (full W=96, h-tile 12+2 halo).
__global__ __launch_bounds__(NTH, 6)
void harris_sum_kernel(const float* __restrict__ x, float* __restrict__ pp) {
    __shared__ float eA[4][NTH];    // A[0], A[1], Dz[0], Dz[1] edges
    __shared__ float eP[12][NTH];   // P[f][0], P[f][1] edges
    __shared__ float red[12];

    const int tid = threadIdx.x;
    const int lh = tid & 15, lc = tid >> 4;   // lc 0..47
    const int c  = blockIdx.z;
    const int H0 = blockIdx.x * 12;
    const int o0 = blockIdx.y * DCH;
    const int gh = H0 + lh - 2;
    const bool rowok = ((unsigned)gh < HH);
    const float mask = rowok ? 1.f : 0.f;     // zero products at OOB rows (box zero-pad)
    const float* xc = x + (size_t)c * DHW;
    const int woff = gh * WW + (lc << 1);
    const bool lok = (lc > 0), rok = (lc < 47);

    // rolling x window: xp=x(e-1), xm=x(e); xn=x(e+1) loaded in-loop
    float xp[2], xm[2], xn[2];
    load2(xp, xc, o0 - 2, woff, rowok);
    load2(xm, xc, o0 - 1, woff, rowok);

    float s2m1[6][2], s2m2[6][2];
    #pragma unroll
    for (int f = 0; f < 6; ++f)
        #pragma unroll
        for (int i = 0; i < 2; ++i) { s2m1[f][i] = 0.f; s2m2[f][i] = 0.f; }
    float hs = 0.f;
    const bool emit_row = (lh >= 2) && (lh <= 13);

    for (int e = o0 - 1; e <= o0 + DCH; ++e) {   // 18 slices -> 16 output slices
        load2(xn, xc, e + 1, woff, rowok);       // x(e+1); occupancy hides latency

        float s2c[6][2];
        if ((unsigned)e < DD) {                  // block-uniform branch
            float A[2], Dz[2];
            #pragma unroll
            for (int i = 0; i < 2; ++i) {
                A[i]  = xp[i] + xm[i] + xn[i];   // depth [1,1,1]
                Dz[i] = xn[i] - xp[i];           // depth [-1,0,1]
            }
            eA[0][tid] = A[0];  eA[1][tid] = A[1];
            eA[2][tid] = Dz[0]; eA[3][tid] = Dz[1];
            __syncthreads();
            float Al = lok ? eA[1][tid - 16] : 0.f;   // left thread's A[1]
            float Dl = lok ? eA[3][tid - 16] : 0.f;
            float Ar = rok ? eA[0][tid + 16] : 0.f;   // right thread's A[0]
            float Dr = rok ? eA[2][tid + 16] : 0.f;

            float P[6][2];
            {   // site 0: w-neighbors (Al, A[0], A[1])
                float Sx = A[1] - Al;
                float Tx = Al + 2.f*A[0] + A[1];
                float Td = Dl + Dz[0] + Dz[1];
                float gx = (dpp_up(Sx) + 2.f*Sx + dpp_dn(Sx)) * mask;  // h [1,2,1]
                float gy = (dpp_dn(Tx) - dpp_up(Tx)) * mask;           // h [-1,0,1]
                float gz = (dpp_up(Td) + Td + dpp_dn(Td)) * mask;      // h [1,1,1]
                P[0][0] = gx*gx; P[1][0] = gy*gy; P[2][0] = gz*gz;
                P[3][0] = gx*gy; P[4][0] = gx*gz; P[5][0] = gy*gz;
            }
            {   // site 1: w-neighbors (A[0], A[1], Ar)
                float Sx = Ar - A[0];
                float Tx = A[0] + 2.f*A[1] + Ar;
                float Td = Dz[0] + Dz[1] + Dr;
                float gx = (dpp_up(Sx) + 2.f*Sx + dpp_dn(Sx)) * mask;
                float gy = (dpp_dn(Tx) - dpp_up(Tx)) * mask;
                float gz = (dpp_up(Td) + Td + dpp_dn(Td)) * mask;
                P[0][1] = gx*gx; P[1][1] = gy*gy; P[2][1] = gz*gz;
                P[3][1] = gx*gy; P[4][1] = gx*gz; P[5][1] = gy*gz;
            }
            #pragma unroll
            for (int f = 0; f < 6; ++f) { eP[2*f][tid] = P[f][0]; eP[2*f+1][tid] = P[f][1]; }
            __syncthreads();
            #pragma unroll
            for (int f = 0; f < 6; ++f) {
                float pl = lok ? eP[2*f+1][tid - 16] : 0.f;
                float pr = rok ? eP[2*f][tid + 16]   : 0.f;
                float R0 = pl      + P[f][0] + P[f][1];
                float R1 = P[f][0] + P[f][1] + pr;
                s2c[f][0] = dpp_up(R0) + R0 + dpp_dn(R0);   // h [1,1,1]
                s2c[f][1] = dpp_up(R1) + R1 + dpp_dn(R1);
            }
        } else {
            #pragma unroll
            for (int f = 0; f < 6; ++f)
                #pragma unroll
                for (int i = 0; i < 2; ++i) s2c[f][i] = 0.f;
        }

        if (e > o0 && emit_row) {   // emit output slice o = e-1
            #pragma unroll
            for (int i = 0; i < 2; ++i) {
                float sxx = s2m2[0][i] + s2m1[0][i] + s2c[0][i];
                float syy = s2m2[1][i] + s2m1[1][i] + s2c[1][i];
                float szz = s2m2[2][i] + s2m1[2][i] + s2c[2][i];
                float sxy = s2m2[3][i] + s2m1[3][i] + s2c[3][i];
                float sxz = s2m2[4][i] + s2m1[4][i] + s2c[4][i];
                float syz = s2m2[5][i] + s2m1[5][i] + s2c[5][i];
                float det = sxx*(syy*szz - syz*syz)
                          - sxy*(sxy*szz - syz*sxz)
                          + sxz*(sxy*syz - syy*sxz);
                float tr = sxx + syy + szz;
                hs += det - KTR * tr * tr;   // unscaled by 27^-3: ranking-invariant
            }
        }
        #pragma unroll
        for (int f = 0; f < 6; ++f)
            #pragma unroll
            for (int i = 0; i < 2; ++i) { s2m2[f][i] = s2m1[f][i]; s2m1[f][i] = s2c[f][i]; }
        #pragma unroll
        for (int i = 0; i < 2; ++i) { xp[i] = xm[i]; xm[i] = xn[i]; }
    }

    // block reduce -> per-block partial slot (no atomics, no ws init needed)
    #pragma unroll
    for (int o = 32; o > 0; o >>= 1) hs += __shfl_down(hs, o, 64);
    if ((tid & 63) == 0) red[tid >> 6] = hs;
    __syncthreads();
    if (tid == 0) {
        float s = 0.f;
        #pragma unroll
        for (int i = 0; i < 12; ++i) s += red[i];
        pp[c * 32 + blockIdx.y * 8 + blockIdx.x] = s * INV27C;
    }
}

// Sum 32 partials/channel, top-8 select (strict >: stable ties), gather copy.
__global__ __launch_bounds__(256)
void gather_topk_kernel(const float* __restrict__ x, const float* __restrict__ pp,
                        float4* __restrict__ out) {
    __shared__ float pv[CCH];
    __shared__ int sidx[8];
    const int tid = threadIdx.x;
    if (tid < CCH) {
        float s = 0.f;
        #pragma unroll
        for (int j = 0; j < 32; ++j) s += pp[tid * 32 + j];
        pv[tid] = s;   // fixed order -> deterministic across blocks
    }
    __syncthreads();
    if (tid == 0) {
        bool used[CCH];
        #pragma unroll
        for (int i = 0; i < CCH; ++i) used[i] = false;
        for (int j = 0; j < 8; ++j) {
            int best = 0; float bv = -__builtin_inff();
            for (int i = 0; i < CCH; ++i)
                if (!used[i] && pv[i] > bv) { bv = pv[i]; best = i; }
            used[best] = true;
            sidx[j] = best;
        }
    }
    __syncthreads();
    const int j   = blockIdx.y;                      // 0..7
    const int pos = blockIdx.x * 256 + tid;          // 576*256 == CH4 exact
    const int cidx = sidx[j];
    const float4* src = (const float4*)(x + (size_t)cidx * DHW);
    out[(size_t)j * CH4 + pos] = src[pos];
}

extern "C" void kernel_launch(void* const* d_in, const int* in_sizes, int n_in,
                              void* d_out, int out_size, void* d_ws, size_t ws_size,
                              hipStream_t stream) {
    const float* x = (const float*)d_in[0];
    float4* out = reinterpret_cast<float4*>(d_out);
    float* pp = (float*)d_ws;                        // 512 per-block partials (2 KB)

    dim3 g1(8, NBY, CCH);                            // (8,4,16) = 512 blocks
    harris_sum_kernel<<<g1, NTH, 0, stream>>>(x, pp);

    dim3 g2(CH4 / 256, 8, 1);                        // (576, 8)
    gather_topk_kernel<<<g2, 256, 0, stream>>>(x, pp, out);
}

// Round 11
// 159.496 us; speedup vs baseline: 3.7147x; 1.0138x over previous
//
#include <hip/hip_runtime.h>

#define CCH 16
#define DD 64
#define HH 96
#define WW 96
#define HW (HH*WW)
#define DHW (DD*HH*WW)   // 589824
#define CH4 (DHW/4)      // 147456
#define NTH 768          // 16 lh x 48 lc, 2 w-sites per thread
#define DCH 16           // depth outputs per block
#define NBY (DD/DCH)     // 4 depth chunks
#define KTR 1.08f        // 27 * k_harris (S unscaled by 1/27; ranking-invariant)
#define INV27C (1.f/19683.f)

typedef float v2f __attribute__((ext_vector_type(2)));

// DPP row16 shifts: thread layout is lh-fast (lh = tid & 15), so a DPP row of
// 16 lanes == one h-column; bound_ctrl=true zero-fills at row ends (filled
// sites only feed non-emitted outputs). Harris is invariant to an up/down swap
// (every term has even degree in each gradient; a swap only flips gy's sign).
__device__ __forceinline__ float dpp_up(float v) {
    return __int_as_float(__builtin_amdgcn_update_dpp(
        0, __float_as_int(v), 0x111 /*row_shr:1*/, 0xF, 0xF, true));
}
__device__ __forceinline__ float dpp_dn(float v) {
    return __int_as_float(__builtin_amdgcn_update_dpp(
        0, __float_as_int(v), 0x101 /*row_shl:1*/, 0xF, 0xF, true));
}

// Depth-sweep separable Harris; thread owns 2 consecutive w sites.
// R11: exchange 3 GRADIENTS (12 LDS ops/slice) instead of 6 products (24),
// w-halo x loaded directly (2 scalar loads) -> eA exchange + one barrier gone.
// Parity-buffered eG keeps WAR safety with a single barrier per slice.
// Two-site math in v2f (ext_vector 2xfp32) to get v_pk_*_f32 packed ops.
// Block: 768 thr = 16 lh x 48 lc (full W=96, h-tile 12+2 halo).
__global__ __launch_bounds__(NTH, 6)
void harris_sum_kernel(const float* __restrict__ x, float* __restrict__ pp) {
    __shared__ float eG[2][6][NTH];   // parity x {gx0,gy0,gz0,gx1,gy1,gz1}
    __shared__ float red[12];

    const int tid = threadIdx.x;
    const int lh = tid & 15, lc = tid >> 4;   // lc 0..47
    const int c  = blockIdx.z;
    const int H0 = blockIdx.x * 12;
    const int o0 = blockIdx.y * DCH;
    const int gh = H0 + lh - 2;
    const bool rowok = ((unsigned)gh < HH);
    const float mask = rowok ? 1.f : 0.f;     // zero products at OOB rows (box zero-pad)
    const float* xc = x + (size_t)c * DHW;
    const int woff = gh * WW + (lc << 1);
    const bool lok = (lc > 0), rok = (lc < 47);

    // window per slice: own pair (v2f) + left/right halo scalars
    v2f xp2, xm2, xn2;
    float xpl, xpr, xml, xmr, xnl, xnr;

    auto loadslice = [&](int e, v2f& o2, float& ol, float& orr) {
        if (rowok && (unsigned)e < DD) {
            const float* s = xc + (size_t)e * HW + woff;
            const float2 t = *(const float2*)s;
            o2.x = t.x; o2.y = t.y;
            ol  = lok ? s[-1] : 0.f;   // x at w-1 (sobel zero-pad at w edges)
            orr = rok ? s[2]  : 0.f;   // x at w+2
        } else {
            o2.x = 0.f; o2.y = 0.f; ol = 0.f; orr = 0.f;
        }
    };

    loadslice(o0 - 2, xp2, xpl, xpr);
    loadslice(o0 - 1, xm2, xml, xmr);

    v2f s2m1[6], s2m2[6];
    #pragma unroll
    for (int f = 0; f < 6; ++f) {
        s2m1[f].x = 0.f; s2m1[f].y = 0.f;
        s2m2[f].x = 0.f; s2m2[f].y = 0.f;
    }
    v2f hv; hv.x = 0.f; hv.y = 0.f;
    const bool emit_row = (lh >= 2) && (lh <= 13);

    for (int e = o0 - 1; e <= o0 + DCH; ++e) {   // 18 slices -> 16 output slices
        loadslice(e + 1, xn2, xnl, xnr);
        const int par = e & 1;

        v2f s2c[6];
        if ((unsigned)e < DD) {                  // block-uniform branch
            const v2f A2  = xp2 + xm2 + xn2;     // depth [1,1,1] (pk)
            const v2f Dz2 = xn2 - xp2;           // depth [-1,0,1] (pk)
            const float Al  = xpl + xml + xnl, Ar  = xpr + xmr + xnr;
            const float Dzl = xnl - xpl,       Dzr = xnr - xpr;

            // w-convs at the 2 own sites (register-internal, halo from loads)
            const float Sx0 = A2.y - Al,              Sx1 = Ar - A2.x;
            const float Tx0 = Al + 2.f*A2.x + A2.y,   Tx1 = A2.x + 2.f*A2.y + Ar;
            const float Td0 = Dzl + Dz2.x + Dz2.y,    Td1 = Dz2.x + Dz2.y + Dzr;

            // h-convs via DPP (VALU pipe)
            const float gx0 = (dpp_up(Sx0) + 2.f*Sx0 + dpp_dn(Sx0)) * mask;
            const float gy0 = (dpp_dn(Tx0) - dpp_up(Tx0)) * mask;
            const float gz0 = (dpp_up(Td0) + Td0 + dpp_dn(Td0)) * mask;
            const float gx1 = (dpp_up(Sx1) + 2.f*Sx1 + dpp_dn(Sx1)) * mask;
            const float gy1 = (dpp_dn(Tx1) - dpp_up(Tx1)) * mask;
            const float gz1 = (dpp_up(Td1) + Td1 + dpp_dn(Td1)) * mask;

            // exchange gradients (6 writes + 6 reads, single barrier, parity WAR-safe)
            eG[par][0][tid] = gx0; eG[par][1][tid] = gy0; eG[par][2][tid] = gz0;
            eG[par][3][tid] = gx1; eG[par][4][tid] = gy1; eG[par][5][tid] = gz1;
            __syncthreads();
            float glx = 0.f, gly = 0.f, glz = 0.f, grx = 0.f, gry = 0.f, grz = 0.f;
            if (lok) { glx = eG[par][3][tid-16]; gly = eG[par][4][tid-16]; glz = eG[par][5][tid-16]; }
            if (rok) { grx = eG[par][0][tid+16]; gry = eG[par][1][tid+16]; grz = eG[par][2][tid+16]; }

            // products: own pair packed, halo scalar (recomputed locally)
            v2f gxv, gyv, gzv;
            gxv.x = gx0; gxv.y = gx1; gyv.x = gy0; gyv.y = gy1; gzv.x = gz0; gzv.y = gz1;
            const v2f Pxx = gxv*gxv, Pyy = gyv*gyv, Pzz = gzv*gzv;
            const v2f Pxy = gxv*gyv, Pxz = gxv*gzv, Pyz = gyv*gzv;
            const float Plxx = glx*glx, Plyy = gly*gly, Plzz = glz*glz;
            const float Plxy = glx*gly, Plxz = glx*glz, Plyz = gly*glz;
            const float Prxx = grx*grx, Pryy = gry*gry, Przz = grz*grz;
            const float Prxy = grx*gry, Prxz = grx*grz, Pryz = gry*grz;

            // w [1,1,1] on products + h [1,1,1] via DPP
            #define FIELD(f, Pv, Pl, Pr)                                   \
            {   const float s_ = (Pv).x + (Pv).y;                          \
                const float R0 = (Pl) + s_, R1 = s_ + (Pr);                \
                s2c[f].x = dpp_up(R0) + R0 + dpp_dn(R0);                   \
                s2c[f].y = dpp_up(R1) + R1 + dpp_dn(R1); }
            FIELD(0, Pxx, Plxx, Prxx)
            FIELD(1, Pyy, Plyy, Pryy)
            FIELD(2, Pzz, Plzz, Przz)
            FIELD(3, Pxy, Plxy, Prxy)
            FIELD(4, Pxz, Plxz, Prxz)
            FIELD(5, Pyz, Plyz, Pryz)
            #undef FIELD
        } else {
            #pragma unroll
            for (int f = 0; f < 6; ++f) { s2c[f].x = 0.f; s2c[f].y = 0.f; }
        }

        if (e > o0 && emit_row) {   // emit output slice o = e-1 (packed math)
            const v2f sxx = s2m2[0] + s2m1[0] + s2c[0];
            const v2f syy = s2m2[1] + s2m1[1] + s2c[1];
            const v2f szz = s2m2[2] + s2m1[2] + s2c[2];
            const v2f sxy = s2m2[3] + s2m1[3] + s2c[3];
            const v2f sxz = s2m2[4] + s2m1[4] + s2c[4];
            const v2f syz = s2m2[5] + s2m1[5] + s2c[5];
            const v2f det = sxx*(syy*szz - syz*syz)
                          - sxy*(sxy*szz - syz*sxz)
                          + sxz*(sxy*syz - syy*sxz);
            const v2f tr = sxx + syy + szz;
            hv += det - KTR * (tr * tr);   // unscaled by 27^-3: ranking-invariant
        }
        #pragma unroll
        for (int f = 0; f < 6; ++f) { s2m2[f] = s2m1[f]; s2m1[f] = s2c[f]; }
        xp2 = xm2; xpl = xml; xpr = xmr;
        xm2 = xn2; xml = xnl; xmr = xnr;
    }

    float hs = hv.x + hv.y;
    // block reduce -> per-block partial slot (no atomics, no ws init needed)
    #pragma unroll
    for (int o = 32; o > 0; o >>= 1) hs += __shfl_down(hs, o, 64);
    if ((tid & 63) == 0) red[tid >> 6] = hs;
    __syncthreads();
    if (tid == 0) {
        float s = 0.f;
        #pragma unroll
        for (int i = 0; i < 12; ++i) s += red[i];
        pp[c * 32 + blockIdx.y * 8 + blockIdx.x] = s * INV27C;
    }
}

// Sum 32 partials/channel, top-8 select (strict >: stable ties), gather copy.
__global__ __launch_bounds__(256)
void gather_topk_kernel(const float* __restrict__ x, const float* __restrict__ pp,
                        float4* __restrict__ out) {
    __shared__ float pv[CCH];
    __shared__ int sidx[8];
    const int tid = threadIdx.x;
    if (tid < CCH) {
        float s = 0.f;
        #pragma unroll
        for (int j = 0; j < 32; ++j) s += pp[tid * 32 + j];
        pv[tid] = s;   // fixed order -> deterministic across blocks
    }
    __syncthreads();
    if (tid == 0) {
        bool used[CCH];
        #pragma unroll
        for (int i = 0; i < CCH; ++i) used[i] = false;
        for (int j = 0; j < 8; ++j) {
            int best = 0; float bv = -__builtin_inff();
            for (int i = 0; i < CCH; ++i)
                if (!used[i] && pv[i] > bv) { bv = pv[i]; best = i; }
            used[best] = true;
            sidx[j] = best;
        }
    }
    __syncthreads();
    const int j   = blockIdx.y;                      // 0..7
    const int pos = blockIdx.x * 256 + tid;          // 576*256 == CH4 exact
    const int cidx = sidx[j];
    const float4* src = (const float4*)(x + (size_t)cidx * DHW);
    out[(size_t)j * CH4 + pos] = src[pos];
}

extern "C" void kernel_launch(void* const* d_in, const int* in_sizes, int n_in,
                              void* d_out, int out_size, void* d_ws, size_t ws_size,
                              hipStream_t stream) {
    const float* x = (const float*)d_in[0];
    float4* out = reinterpret_cast<float4*>(d_out);
    float* pp = (float*)d_ws;                        // 512 per-block partials (2 KB)

    dim3 g1(8, NBY, CCH);                            // (8,4,16) = 512 blocks
    harris_sum_kernel<<<g1, NTH, 0, stream>>>(x, pp);

    dim3 g2(CH4 / 256, 8, 1);                        // (576, 8)
    gather_topk_kernel<<<g2, 256, 0, stream>>>(x, pp, out);
}